// Round 9
// baseline (328.545 us; speedup 1.0000x reference)
//
#include <hip/hip_runtime.h>
#include <hip/hip_bf16.h>

#define NN 40000
#define NE 640000
#define HID 128
#define NCLS 10
#define NGRAPH 16
#define GB 313              // gemm blocks: 313*128 = 40064 rows
#define NNP (GB * 128)      // padded feature rows

typedef __attribute__((ext_vector_type(8))) short bf16x8;
typedef __attribute__((ext_vector_type(4))) float f32x4;

__device__ inline float bf2f(unsigned short u) {
    unsigned int x = ((unsigned int)u) << 16;
    return __builtin_bit_cast(float, x);
}
__device__ inline unsigned short f2bf(float f) {
    __hip_bfloat16 h = __float2bfloat16(f);
    return __builtin_bit_cast(unsigned short, h);
}

// ---------------- degree count ----------------
__global__ void k_count_deg(const int* __restrict__ dst, int* __restrict__ deg, int n) {
    int e = blockIdx.x * blockDim.x + threadIdx.x;
    if (e < n) atomicAdd(&deg[__builtin_nontemporal_load(dst + e)], 1);
}

// ---------------- scan stage 1: per-block exclusive scan + block totals (+ fused norm) ----------------
__global__ __launch_bounds__(1024) void k_scan1(const int* __restrict__ deg, int* __restrict__ row_start,
                                                int* __restrict__ partial, float* __restrict__ norm) {
    __shared__ int wsum[16];
    int tid = threadIdx.x, lane = tid & 63, wid = tid >> 6;
    int i = blockIdx.x * 1024 + tid;
    int v = (i < NN) ? deg[i] : 0;
    if (i < NN) norm[i] = rsqrtf(fmaxf((float)v, 1.0f));
    int sv = v;
    #pragma unroll
    for (int off = 1; off < 64; off <<= 1) {
        int t = __shfl_up(sv, off);
        if (lane >= off) sv += t;
    }
    if (lane == 63) wsum[wid] = sv;
    __syncthreads();
    if (wid == 0) {
        int ws = (lane < 16) ? wsum[lane] : 0;
        #pragma unroll
        for (int off = 1; off < 16; off <<= 1) {
            int t = __shfl_up(ws, off);
            if (lane >= off) ws += t;
        }
        if (lane < 16) wsum[lane] = ws;
    }
    __syncthreads();
    int excl = (wid > 0 ? wsum[wid - 1] : 0) + (sv - v);
    if (i < NN) row_start[i] = excl;
    if (tid == 0) partial[blockIdx.x] = wsum[15];
}

// ---------------- scan stage 2 (merged): add carry, emit cursor copy, write total ----------------
__global__ __launch_bounds__(1024) void k_scan3(int* __restrict__ row_start, const int* __restrict__ partial,
                                                int* __restrict__ cursor, int nb) {
    __shared__ int sh_carry, sh_all;
    int tid = threadIdx.x;
    if (tid < 64) {
        int v = (tid < nb) ? partial[tid] : 0;
        int lt = (tid < (int)blockIdx.x) ? v : 0;
        #pragma unroll
        for (int off = 32; off; off >>= 1) {
            lt += __shfl_down(lt, off);
            v  += __shfl_down(v, off);
        }
        if (tid == 0) { sh_carry = lt; sh_all = v; }
    }
    __syncthreads();
    int i = blockIdx.x * 1024 + tid;
    if (i < NN) {
        int val = row_start[i] + sh_carry;
        row_start[i] = val;
        cursor[i] = val;
    }
    if (blockIdx.x == 0 && tid == 0) row_start[NN] = sh_all;
}

// ---------------- CSR bucket fill (cursor-based) ----------------
__global__ void k_fill_csr(const int* __restrict__ src, const int* __restrict__ dst,
                           int* __restrict__ cursor, int* __restrict__ csr_src, int n) {
    int e = blockIdx.x * blockDim.x + threadIdx.x;
    if (e < n) {
        int d = __builtin_nontemporal_load(dst + e);
        int sv = __builtin_nontemporal_load(src + e);
        int pos = atomicAdd(&cursor[d], 1);
        csr_src[pos] = sv;
    }
}

// ---------------- converts ----------------
__global__ void k_cvt_h(const float* __restrict__ h, unsigned short* __restrict__ hb) {
    int i = blockIdx.x * 256 + threadIdx.x;
    if (i < NN * HID / 4) {
        float4 v = reinterpret_cast<const float4*>(h)[i];
        ushort4 o;
        o.x = f2bf(v.x); o.y = f2bf(v.y); o.z = f2bf(v.z); o.w = f2bf(v.w);
        reinterpret_cast<ushort4*>(hb)[i] = o;
    }
}

// W[384][128] fp32 -> Wt[128][384] bf16 (both weights; blockIdx.y selects)
__global__ void k_cvt_wt(const float* __restrict__ W1, const float* __restrict__ W2,
                         unsigned short* __restrict__ W1t, unsigned short* __restrict__ W2t) {
    int t = blockIdx.x * 256 + threadIdx.x;
    const float* W = blockIdx.y ? W2 : W1;
    unsigned short* Wt = blockIdx.y ? W2t : W1t;
    if (t < 384 * HID) {
        int c = t / 384, k = t % 384;
        Wt[t] = f2bf(W[(size_t)k * HID + c]);
    }
}

// ---------------- propagation: one node per 64-lane wave (unchanged from r6/r8) ----------------
__global__ __launch_bounds__(256) void k_prop_bf(const unsigned short* __restrict__ x, const float* __restrict__ norm,
                                                 const int* __restrict__ row_start, const int* __restrict__ csr_src,
                                                 unsigned short* __restrict__ y) {
    int node = blockIdx.x * 4 + threadIdx.y;
    int lane = threadIdx.x;
    int h = lane >> 5;
    int sub = lane & 31;
    int colb = sub * 4;
    float a0 = 0.f, a1 = 0.f, a2 = 0.f, a3 = 0.f;
    int s = row_start[node], e = row_start[node + 1];
    int i = s + h;
    if (i + 6 < e) {
        int c0 = csr_src[i], c1 = csr_src[i + 2], c2 = csr_src[i + 4], c3 = csr_src[i + 6];
        int j = i + 8;
        while (true) {
            bool more = (j + 6 < e);
            int n0, n1, n2, n3;
            if (more) {
                n0 = csr_src[j]; n1 = csr_src[j + 2]; n2 = csr_src[j + 4]; n3 = csr_src[j + 6];
            }
            float s0 = norm[c0], s1 = norm[c1], s2 = norm[c2], s3 = norm[c3];
            ushort4 v0 = *reinterpret_cast<const ushort4*>(x + (size_t)c0 * HID + colb);
            ushort4 v1 = *reinterpret_cast<const ushort4*>(x + (size_t)c1 * HID + colb);
            ushort4 v2 = *reinterpret_cast<const ushort4*>(x + (size_t)c2 * HID + colb);
            ushort4 v3 = *reinterpret_cast<const ushort4*>(x + (size_t)c3 * HID + colb);
            a0 += s0 * bf2f(v0.x) + s1 * bf2f(v1.x) + s2 * bf2f(v2.x) + s3 * bf2f(v3.x);
            a1 += s0 * bf2f(v0.y) + s1 * bf2f(v1.y) + s2 * bf2f(v2.y) + s3 * bf2f(v3.y);
            a2 += s0 * bf2f(v0.z) + s1 * bf2f(v1.z) + s2 * bf2f(v2.z) + s3 * bf2f(v3.z);
            a3 += s0 * bf2f(v0.w) + s1 * bf2f(v1.w) + s2 * bf2f(v2.w) + s3 * bf2f(v3.w);
            i = j;
            if (!more) break;
            c0 = n0; c1 = n1; c2 = n2; c3 = n3;
            j += 8;
        }
    }
    for (; i < e; i += 2) {
        int sn = csr_src[i];
        float ns = norm[sn];
        ushort4 v = *reinterpret_cast<const ushort4*>(x + (size_t)sn * HID + colb);
        a0 += ns * bf2f(v.x); a1 += ns * bf2f(v.y); a2 += ns * bf2f(v.z); a3 += ns * bf2f(v.w);
    }
    a0 += __shfl_xor(a0, 32);
    a1 += __shfl_xor(a1, 32);
    a2 += __shfl_xor(a2, 32);
    a3 += __shfl_xor(a3, 32);
    if (h == 0) {
        float nd = norm[node];
        ushort4 o;
        o.x = f2bf(nd * a0); o.y = f2bf(nd * a1); o.z = f2bf(nd * a2); o.w = f2bf(nd * a3);
        *reinterpret_cast<ushort4*>(y + (size_t)node * HID + colb) = o;
    }
}

// ---------------- MFMA GEMM: 4 waves x 32 rows, optional fused max-pool ----------------
// If y != nullptr: write relu output rows < NN. Else: atomicMax into pooled[gid[row]].
__global__ __launch_bounds__(256) void k_gemm_mfma(const unsigned short* __restrict__ x0,
                                                   const unsigned short* __restrict__ x1,
                                                   const unsigned short* __restrict__ x2,
                                                   const unsigned short* __restrict__ Wt,
                                                   const float* __restrict__ bias,
                                                   unsigned short* __restrict__ y,
                                                   const int* __restrict__ gid,
                                                   float* __restrict__ pooled) {
    int tid = threadIdx.x;
    int wave = tid >> 6;
    int lane = tid & 63;
    int r = lane & 15, kg = lane >> 4;
    int row0 = blockIdx.x * 128 + wave * 32;
    if (row0 >= NN) return;  // fully-pad wave
    const unsigned short* xs[3] = { x0, x1, x2 };

    f32x4 acc[2][8];
    #pragma unroll
    for (int rf = 0; rf < 2; ++rf)
        #pragma unroll
        for (int cf = 0; cf < 8; ++cf) acc[rf][cf] = (f32x4){0.f, 0.f, 0.f, 0.f};

    #pragma unroll
    for (int kseg = 0; kseg < 3; ++kseg) {
        const unsigned short* __restrict__ xpA = xs[kseg] + (size_t)(row0 + r) * HID;
        const unsigned short* __restrict__ xpB = xpA + 16 * HID;
        #pragma unroll
        for (int kb = 0; kb < 4; ++kb) {
            bf16x8 a0 = *reinterpret_cast<const bf16x8*>(xpA + kb * 32 + kg * 8);
            bf16x8 a1 = *reinterpret_cast<const bf16x8*>(xpB + kb * 32 + kg * 8);
            #pragma unroll
            for (int cf = 0; cf < 8; ++cf) {
                bf16x8 b = *reinterpret_cast<const bf16x8*>(
                    Wt + (size_t)(cf * 16 + r) * 384 + kseg * 128 + kb * 32 + kg * 8);
                acc[0][cf] = __builtin_amdgcn_mfma_f32_16x16x32_bf16(a0, b, acc[0][cf], 0, 0, 0);
                acc[1][cf] = __builtin_amdgcn_mfma_f32_16x16x32_bf16(a1, b, acc[1][cf], 0, 0, 0);
            }
        }
    }
    int colr = lane & 15;
    int vb = (lane >> 4) * 4;
    #pragma unroll
    for (int rf = 0; rf < 2; ++rf) {
        int orow = row0 + rf * 16 + vb;
        if (y) {
            #pragma unroll
            for (int cf = 0; cf < 8; ++cf) {
                int col = cf * 16 + colr;
                float bb = bias[col];
                #pragma unroll
                for (int v = 0; v < 4; ++v) {
                    int row = orow + v;
                    if (row < NN) {
                        float val = fmaxf(acc[rf][cf][v] + bb, 0.f);
                        y[(size_t)row * HID + col] = f2bf(val);
                    }
                }
            }
        } else {
            int gg[4];
            #pragma unroll
            for (int v = 0; v < 4; ++v) {
                int row = orow + v;
                gg[v] = (row < NN) ? gid[row] : -1;
            }
            #pragma unroll
            for (int cf = 0; cf < 8; ++cf) {
                int col = cf * 16 + colr;
                float bb = bias[col];
                float m = 0.f;
                int cg = gg[0];
                bool any = false;
                #pragma unroll
                for (int v = 0; v < 4; ++v) {
                    if (gg[v] >= 0) {
                        float val = fmaxf(acc[rf][cf][v] + bb, 0.f);
                        if (gg[v] != cg) {
                            if (any) atomicMax((unsigned int*)&pooled[cg * HID + col], __float_as_uint(m));
                            m = 0.f; cg = gg[v];
                        }
                        m = fmaxf(m, val);
                        any = true;
                    }
                }
                if (any) atomicMax((unsigned int*)&pooled[cg * HID + col], __float_as_uint(m));
            }
        }
    }
}

// ---------------- final head ----------------
__global__ void k_head(const float* __restrict__ pooled, const float* __restrict__ Wc,
                       const float* __restrict__ bc, float* __restrict__ out) {
    int t = threadIdx.x;
    if (t < NGRAPH * NCLS) {
        int g = t / NCLS, c = t % NCLS;
        float acc = bc[c];
        for (int k = 0; k < HID; ++k) acc += pooled[g * HID + k] * Wc[k * NCLS + c];
        out[t] = acc;
    }
}

extern "C" void kernel_launch(void* const* d_in, const int* in_sizes, int n_in,
                              void* d_out, int out_size, void* d_ws, size_t ws_size,
                              hipStream_t stream) {
    const float* h   = (const float*)d_in[0];
    const int*   src = (const int*)d_in[1];
    const int*   dst = (const int*)d_in[2];
    const int*   gid = (const int*)d_in[3];
    const float* W1  = (const float*)d_in[4];
    const float* b1  = (const float*)d_in[5];
    const float* W2  = (const float*)d_in[6];
    const float* b2  = (const float*)d_in[7];
    const float* Wc  = (const float*)d_in[8];
    const float* bc  = (const float*)d_in[9];
    float* out = (float*)d_out;

    char* ws = (char*)d_ws;
    size_t off = 0;
    auto alloc = [&](size_t bytes) { void* p = ws + off; off = (off + bytes + 63) & ~(size_t)63; return p; };
    int*   deg       = (int*)alloc((size_t)NN * 4);
    int*   cursor    = (int*)alloc((size_t)NN * 4);
    int*   row_start = (int*)alloc((size_t)(NN + 1) * 4);
    int*   csr_src   = (int*)alloc((size_t)NE * 4);
    float* norm      = (float*)alloc((size_t)NN * 4);
    int*   partial   = (int*)alloc(64 * 4);
    float* pooled    = (float*)alloc((size_t)NGRAPH * HID * 4);
    unsigned short* W1t = (unsigned short*)alloc((size_t)384 * HID * 2);
    unsigned short* W2t = (unsigned short*)alloc((size_t)384 * HID * 2);
    const size_t FB = (size_t)NNP * HID * 2;   // padded to 40064 rows
    unsigned short* hb  = (unsigned short*)alloc(FB);
    unsigned short* Bb  = (unsigned short*)alloc(FB);
    unsigned short* Cb  = (unsigned short*)alloc(FB);
    unsigned short* Yb  = (unsigned short*)alloc(FB);

    hipMemsetAsync(deg, 0, (size_t)NN * 4, stream);
    hipMemsetAsync(pooled, 0, (size_t)NGRAPH * HID * 4, stream);

    const int EB = 256;
    const int SCAN_BLOCKS = (NN + 1023) / 1024;  // 40

    // converts first (independent of graph build)
    k_cvt_h<<<(NN * HID / 4 + 255) / 256, 256, 0, stream>>>(h, hb);
    dim3 wgrid((384 * HID + 255) / 256, 2);
    k_cvt_wt<<<wgrid, 256, 0, stream>>>(W1, W2, W1t, W2t);

    // CSR build
    k_count_deg<<<(NE + EB - 1) / EB, EB, 0, stream>>>(dst, deg, NE);
    k_scan1<<<SCAN_BLOCKS, 1024, 0, stream>>>(deg, row_start, partial, norm);
    k_scan3<<<SCAN_BLOCKS, 1024, 0, stream>>>(row_start, partial, cursor, SCAN_BLOCKS);
    k_fill_csr<<<(NE + EB - 1) / EB, EB, 0, stream>>>(src, dst, cursor, csr_src, NE);

    dim3 pblk(64, 4);
    int pblocks = NN / 4;     // 10000

    // layer 1
    k_prop_bf<<<pblocks, pblk, 0, stream>>>(hb, norm, row_start, csr_src, Bb);
    k_prop_bf<<<pblocks, pblk, 0, stream>>>(Bb, norm, row_start, csr_src, Cb);
    k_gemm_mfma<<<GB, 256, 0, stream>>>(hb, Bb, Cb, W1t, b1, Yb, nullptr, nullptr);

    // layer 2 (fused pool in epilogue; no Z buffer)
    k_prop_bf<<<pblocks, pblk, 0, stream>>>(Yb, norm, row_start, csr_src, Bb);
    k_prop_bf<<<pblocks, pblk, 0, stream>>>(Bb, norm, row_start, csr_src, Cb);
    k_gemm_mfma<<<GB, 256, 0, stream>>>(Yb, Bb, Cb, W2t, b2, nullptr, gid, pooled);

    // head
    k_head<<<1, 192, 0, stream>>>(pooled, Wc, bc, out);
}

// Round 10
// 310.391 us; speedup vs baseline: 1.0585x; 1.0585x over previous
//
#include <hip/hip_runtime.h>
#include <hip/hip_bf16.h>

#define NN 40000
#define NE 640000
#define HID 128
#define NCLS 10
#define NGRAPH 16

typedef __attribute__((ext_vector_type(8))) short bf16x8;
typedef __attribute__((ext_vector_type(4))) float f32x4;

__device__ inline float bf2f(unsigned short u) {
    unsigned int x = ((unsigned int)u) << 16;
    return __builtin_bit_cast(float, x);
}
__device__ inline unsigned short f2bf(float f) {
    __hip_bfloat16 h = __float2bfloat16(f);
    return __builtin_bit_cast(unsigned short, h);
}

// ---------------- degree count ----------------
__global__ void k_count_deg(const int* __restrict__ dst, int* __restrict__ deg, int n) {
    int e = blockIdx.x * blockDim.x + threadIdx.x;
    if (e < n) atomicAdd(&deg[__builtin_nontemporal_load(dst + e)], 1);
}

// ---------------- scan stage 1: per-block exclusive scan + block totals (+ fused norm) ----------------
__global__ __launch_bounds__(1024) void k_scan1(const int* __restrict__ deg, int* __restrict__ row_start,
                                                int* __restrict__ partial, float* __restrict__ norm) {
    __shared__ int wsum[16];
    int tid = threadIdx.x, lane = tid & 63, wid = tid >> 6;
    int i = blockIdx.x * 1024 + tid;
    int v = (i < NN) ? deg[i] : 0;
    if (i < NN) norm[i] = rsqrtf(fmaxf((float)v, 1.0f));
    int sv = v;
    #pragma unroll
    for (int off = 1; off < 64; off <<= 1) {
        int t = __shfl_up(sv, off);
        if (lane >= off) sv += t;
    }
    if (lane == 63) wsum[wid] = sv;
    __syncthreads();
    if (wid == 0) {
        int ws = (lane < 16) ? wsum[lane] : 0;
        #pragma unroll
        for (int off = 1; off < 16; off <<= 1) {
            int t = __shfl_up(ws, off);
            if (lane >= off) ws += t;
        }
        if (lane < 16) wsum[lane] = ws;
    }
    __syncthreads();
    int excl = (wid > 0 ? wsum[wid - 1] : 0) + (sv - v);
    if (i < NN) row_start[i] = excl;
    if (tid == 0) partial[blockIdx.x] = wsum[15];
}

// ---------------- scan stage 2 (merged): add carry, emit cursor copy, write total ----------------
__global__ __launch_bounds__(1024) void k_scan3(int* __restrict__ row_start, const int* __restrict__ partial,
                                                int* __restrict__ cursor, int nb) {
    __shared__ int sh_carry, sh_all;
    int tid = threadIdx.x;
    if (tid < 64) {
        int v = (tid < nb) ? partial[tid] : 0;
        int lt = (tid < (int)blockIdx.x) ? v : 0;
        #pragma unroll
        for (int off = 32; off; off >>= 1) {
            lt += __shfl_down(lt, off);
            v  += __shfl_down(v, off);
        }
        if (tid == 0) { sh_carry = lt; sh_all = v; }
    }
    __syncthreads();
    int i = blockIdx.x * 1024 + tid;
    if (i < NN) {
        int val = row_start[i] + sh_carry;
        row_start[i] = val;
        cursor[i] = val;
    }
    if (blockIdx.x == 0 && tid == 0) row_start[NN] = sh_all;
}

// ---------------- CSR bucket fill (cursor-based) ----------------
__global__ void k_fill_csr(const int* __restrict__ src, const int* __restrict__ dst,
                           int* __restrict__ cursor, int* __restrict__ csr_src, int n) {
    int e = blockIdx.x * blockDim.x + threadIdx.x;
    if (e < n) {
        int d = __builtin_nontemporal_load(dst + e);
        int sv = __builtin_nontemporal_load(src + e);
        int pos = atomicAdd(&cursor[d], 1);
        csr_src[pos] = sv;
    }
}

// ---------------- converts ----------------
__global__ void k_cvt_h(const float* __restrict__ h, unsigned short* __restrict__ hb) {
    int i = blockIdx.x * 256 + threadIdx.x;
    if (i < NN * HID / 4) {
        float4 v = reinterpret_cast<const float4*>(h)[i];
        ushort4 o;
        o.x = f2bf(v.x); o.y = f2bf(v.y); o.z = f2bf(v.z); o.w = f2bf(v.w);
        reinterpret_cast<ushort4*>(hb)[i] = o;
    }
}

// W[384][128] fp32 -> fragment-ordered bf16: Wfrag[(cf*12 + kseg*4 + kb)*64 + lane][8]
// lane: r = lane&15 (output col within frag), kg = lane>>4 (k-subgroup).
// Element j of lane's 16B: W[(kseg*128 + kb*32 + kg*8 + j)*128 + cf*16 + r].
// One thread per (matrix, frag, lane): 2*96*64 = 12288 threads.
__global__ void k_cvt_wfrag(const float* __restrict__ W1, const float* __restrict__ W2,
                            unsigned short* __restrict__ F1, unsigned short* __restrict__ F2) {
    int t = blockIdx.x * 256 + threadIdx.x;
    if (t >= 12288) return;
    int m = t / 6144;
    int u = t - m * 6144;        // 0..6143
    int frag = u >> 6;           // 0..95
    int lane = u & 63;
    int cf = frag / 12;
    int kk = frag - cf * 12;     // kseg*4+kb
    int r = lane & 15, kg = lane >> 4;
    int c = cf * 16 + r;
    int kbase = kk * 32 + kg * 8;   // (kseg*4+kb)*32 == kseg*128 + kb*32
    const float* __restrict__ W = m ? W2 : W1;
    unsigned short* __restrict__ F = m ? F2 : F1;
    unsigned short* __restrict__ o = F + ((size_t)frag * 64 + lane) * 8;
    #pragma unroll
    for (int j = 0; j < 8; ++j)
        o[j] = f2bf(W[(size_t)(kbase + j) * HID + c]);
}

// ---------------- propagation: one node per 64-lane wave ----------------
__global__ __launch_bounds__(256) void k_prop_bf(const unsigned short* __restrict__ x, const float* __restrict__ norm,
                                                 const int* __restrict__ row_start, const int* __restrict__ csr_src,
                                                 unsigned short* __restrict__ y) {
    int node = blockIdx.x * 4 + threadIdx.y;
    int lane = threadIdx.x;
    int h = lane >> 5;
    int sub = lane & 31;
    int colb = sub * 4;
    float a0 = 0.f, a1 = 0.f, a2 = 0.f, a3 = 0.f;
    int s = row_start[node], e = row_start[node + 1];
    int i = s + h;
    if (i + 6 < e) {
        int c0 = csr_src[i], c1 = csr_src[i + 2], c2 = csr_src[i + 4], c3 = csr_src[i + 6];
        int j = i + 8;
        while (true) {
            bool more = (j + 6 < e);
            int n0, n1, n2, n3;
            if (more) {
                n0 = csr_src[j]; n1 = csr_src[j + 2]; n2 = csr_src[j + 4]; n3 = csr_src[j + 6];
            }
            float s0 = norm[c0], s1 = norm[c1], s2 = norm[c2], s3 = norm[c3];
            ushort4 v0 = *reinterpret_cast<const ushort4*>(x + (size_t)c0 * HID + colb);
            ushort4 v1 = *reinterpret_cast<const ushort4*>(x + (size_t)c1 * HID + colb);
            ushort4 v2 = *reinterpret_cast<const ushort4*>(x + (size_t)c2 * HID + colb);
            ushort4 v3 = *reinterpret_cast<const ushort4*>(x + (size_t)c3 * HID + colb);
            a0 += s0 * bf2f(v0.x) + s1 * bf2f(v1.x) + s2 * bf2f(v2.x) + s3 * bf2f(v3.x);
            a1 += s0 * bf2f(v0.y) + s1 * bf2f(v1.y) + s2 * bf2f(v2.y) + s3 * bf2f(v3.y);
            a2 += s0 * bf2f(v0.z) + s1 * bf2f(v1.z) + s2 * bf2f(v2.z) + s3 * bf2f(v3.z);
            a3 += s0 * bf2f(v0.w) + s1 * bf2f(v1.w) + s2 * bf2f(v2.w) + s3 * bf2f(v3.w);
            i = j;
            if (!more) break;
            c0 = n0; c1 = n1; c2 = n2; c3 = n3;
            j += 8;
        }
    }
    for (; i < e; i += 2) {
        int sn = csr_src[i];
        float ns = norm[sn];
        ushort4 v = *reinterpret_cast<const ushort4*>(x + (size_t)sn * HID + colb);
        a0 += ns * bf2f(v.x); a1 += ns * bf2f(v.y); a2 += ns * bf2f(v.z); a3 += ns * bf2f(v.w);
    }
    a0 += __shfl_xor(a0, 32);
    a1 += __shfl_xor(a1, 32);
    a2 += __shfl_xor(a2, 32);
    a3 += __shfl_xor(a3, 32);
    if (h == 0) {
        float nd = norm[node];
        ushort4 o;
        o.x = f2bf(nd * a0); o.y = f2bf(nd * a1); o.z = f2bf(nd * a2); o.w = f2bf(nd * a3);
        *reinterpret_cast<ushort4*>(y + (size_t)node * HID + colb) = o;
    }
}

// ---------------- MFMA GEMM: 2 waves x 16 rows, coalesced frag-ordered B, optional fused pool ----------------
__global__ __launch_bounds__(128) void k_gemm_mfma(const unsigned short* __restrict__ x0,
                                                   const unsigned short* __restrict__ x1,
                                                   const unsigned short* __restrict__ x2,
                                                   const unsigned short* __restrict__ Wfrag,
                                                   const float* __restrict__ bias,
                                                   unsigned short* __restrict__ y,
                                                   const int* __restrict__ gid,
                                                   float* __restrict__ pooled) {
    int tid = threadIdx.x;
    int wave = tid >> 6;
    int lane = tid & 63;
    int r = lane & 15, kg = lane >> 4;
    int row0 = blockIdx.x * 32 + wave * 16;
    const unsigned short* xs[3] = { x0, x1, x2 };

    f32x4 acc[8];
    #pragma unroll
    for (int cf = 0; cf < 8; ++cf) acc[cf] = (f32x4){0.f, 0.f, 0.f, 0.f};

    #pragma unroll
    for (int kseg = 0; kseg < 3; ++kseg) {
        const unsigned short* __restrict__ xp = xs[kseg] + (size_t)(row0 + r) * HID;
        #pragma unroll
        for (int kb = 0; kb < 4; ++kb) {
            bf16x8 afrag = *reinterpret_cast<const bf16x8*>(xp + kb * 32 + kg * 8);
            #pragma unroll
            for (int cf = 0; cf < 8; ++cf) {
                bf16x8 bfrag = *reinterpret_cast<const bf16x8*>(
                    Wfrag + ((size_t)(cf * 12 + kseg * 4 + kb) * 64 + lane) * 8);
                acc[cf] = __builtin_amdgcn_mfma_f32_16x16x32_bf16(afrag, bfrag, acc[cf], 0, 0, 0);
            }
        }
    }
    int colr = lane & 15;
    int orow = row0 + (lane >> 4) * 4;
    if (y) {
        #pragma unroll
        for (int cf = 0; cf < 8; ++cf) {
            int col = cf * 16 + colr;
            float bb = bias[col];
            #pragma unroll
            for (int v = 0; v < 4; ++v) {
                float val = fmaxf(acc[cf][v] + bb, 0.f);
                y[(size_t)(orow + v) * HID + col] = f2bf(val);
            }
        }
    } else {
        int gg[4];
        #pragma unroll
        for (int v = 0; v < 4; ++v) gg[v] = gid[orow + v];
        #pragma unroll
        for (int cf = 0; cf < 8; ++cf) {
            int col = cf * 16 + colr;
            float bb = bias[col];
            float m = 0.f;
            int cg = gg[0];
            #pragma unroll
            for (int v = 0; v < 4; ++v) {
                float val = fmaxf(acc[cf][v] + bb, 0.f);
                if (gg[v] != cg) {
                    atomicMax((unsigned int*)&pooled[cg * HID + col], __float_as_uint(m));
                    m = 0.f; cg = gg[v];
                }
                m = fmaxf(m, val);
            }
            atomicMax((unsigned int*)&pooled[cg * HID + col], __float_as_uint(m));
        }
    }
}

// ---------------- final head ----------------
__global__ void k_head(const float* __restrict__ pooled, const float* __restrict__ Wc,
                       const float* __restrict__ bc, float* __restrict__ out) {
    int t = threadIdx.x;
    if (t < NGRAPH * NCLS) {
        int g = t / NCLS, c = t % NCLS;
        float acc = bc[c];
        for (int k = 0; k < HID; ++k) acc += pooled[g * HID + k] * Wc[k * NCLS + c];
        out[t] = acc;
    }
}

extern "C" void kernel_launch(void* const* d_in, const int* in_sizes, int n_in,
                              void* d_out, int out_size, void* d_ws, size_t ws_size,
                              hipStream_t stream) {
    const float* h   = (const float*)d_in[0];
    const int*   src = (const int*)d_in[1];
    const int*   dst = (const int*)d_in[2];
    const int*   gid = (const int*)d_in[3];
    const float* W1  = (const float*)d_in[4];
    const float* b1  = (const float*)d_in[5];
    const float* W2  = (const float*)d_in[6];
    const float* b2  = (const float*)d_in[7];
    const float* Wc  = (const float*)d_in[8];
    const float* bc  = (const float*)d_in[9];
    float* out = (float*)d_out;

    char* ws = (char*)d_ws;
    size_t off = 0;
    auto alloc = [&](size_t bytes) { void* p = ws + off; off = (off + bytes + 63) & ~(size_t)63; return p; };
    int*   deg       = (int*)alloc((size_t)NN * 4);
    int*   cursor    = (int*)alloc((size_t)NN * 4);
    int*   row_start = (int*)alloc((size_t)(NN + 1) * 4);
    int*   csr_src   = (int*)alloc((size_t)NE * 4);
    float* norm      = (float*)alloc((size_t)NN * 4);
    int*   partial   = (int*)alloc(64 * 4);
    float* pooled    = (float*)alloc((size_t)NGRAPH * HID * 4);
    unsigned short* Wf1 = (unsigned short*)alloc((size_t)384 * HID * 2);
    unsigned short* Wf2 = (unsigned short*)alloc((size_t)384 * HID * 2);
    const size_t FB = (size_t)NN * HID * 2;
    unsigned short* hb  = (unsigned short*)alloc(FB);
    unsigned short* Bb  = (unsigned short*)alloc(FB);
    unsigned short* Cb  = (unsigned short*)alloc(FB);
    unsigned short* Yb  = (unsigned short*)alloc(FB);

    hipMemsetAsync(deg, 0, (size_t)NN * 4, stream);
    hipMemsetAsync(pooled, 0, (size_t)NGRAPH * HID * 4, stream);

    const int EB = 256;
    const int SCAN_BLOCKS = (NN + 1023) / 1024;  // 40

    // converts first (independent of graph build)
    k_cvt_h<<<(NN * HID / 4 + 255) / 256, 256, 0, stream>>>(h, hb);
    k_cvt_wfrag<<<48, 256, 0, stream>>>(W1, W2, Wf1, Wf2);

    // CSR build
    k_count_deg<<<(NE + EB - 1) / EB, EB, 0, stream>>>(dst, deg, NE);
    k_scan1<<<SCAN_BLOCKS, 1024, 0, stream>>>(deg, row_start, partial, norm);
    k_scan3<<<SCAN_BLOCKS, 1024, 0, stream>>>(row_start, partial, cursor, SCAN_BLOCKS);
    k_fill_csr<<<(NE + EB - 1) / EB, EB, 0, stream>>>(src, dst, cursor, csr_src, NE);

    dim3 pblk(64, 4);
    int pblocks = NN / 4;     // 10000
    int gblocks = NN / 32;    // 1250

    // layer 1
    k_prop_bf<<<pblocks, pblk, 0, stream>>>(hb, norm, row_start, csr_src, Bb);
    k_prop_bf<<<pblocks, pblk, 0, stream>>>(Bb, norm, row_start, csr_src, Cb);
    k_gemm_mfma<<<gblocks, 128, 0, stream>>>(hb, Bb, Cb, Wf1, b1, Yb, nullptr, nullptr);

    // layer 2 (fused max-pool epilogue; no Z buffer)
    k_prop_bf<<<pblocks, pblk, 0, stream>>>(Yb, norm, row_start, csr_src, Bb);
    k_prop_bf<<<pblocks, pblk, 0, stream>>>(Bb, norm, row_start, csr_src, Cb);
    k_gemm_mfma<<<gblocks, 128, 0, stream>>>(Yb, Bb, Cb, Wf2, b2, nullptr, gid, pooled);

    // head
    k_head<<<1, 192, 0, stream>>>(pooled, Wc, bc, out);
}

// Round 11
// 240.567 us; speedup vs baseline: 1.3657x; 1.2902x over previous
//
#include <hip/hip_runtime.h>
#include <hip/hip_bf16.h>

#define NN 40000
#define NE 640000
#define HID 128
#define NCLS 10
#define NGRAPH 16

typedef __attribute__((ext_vector_type(8))) short bf16x8;
typedef __attribute__((ext_vector_type(4))) float f32x4;

__device__ inline float bf2f(unsigned short u) {
    unsigned int x = ((unsigned int)u) << 16;
    return __builtin_bit_cast(float, x);
}
__device__ inline unsigned short f2bf(float f) {
    __hip_bfloat16 h = __float2bfloat16(f);
    return __builtin_bit_cast(unsigned short, h);
}

// ---------------- degree count ----------------
__global__ void k_count_deg(const int* __restrict__ dst, int* __restrict__ deg, int n) {
    int e = blockIdx.x * blockDim.x + threadIdx.x;
    if (e < n) atomicAdd(&deg[__builtin_nontemporal_load(dst + e)], 1);
}

// ---------------- scan stage 1: per-block exclusive scan + block totals (+ fused norm) ----------------
__global__ __launch_bounds__(1024) void k_scan1(const int* __restrict__ deg, int* __restrict__ row_start,
                                                int* __restrict__ partial, float* __restrict__ norm) {
    __shared__ int wsum[16];
    int tid = threadIdx.x, lane = tid & 63, wid = tid >> 6;
    int i = blockIdx.x * 1024 + tid;
    int v = (i < NN) ? deg[i] : 0;
    if (i < NN) norm[i] = rsqrtf(fmaxf((float)v, 1.0f));
    int sv = v;
    #pragma unroll
    for (int off = 1; off < 64; off <<= 1) {
        int t = __shfl_up(sv, off);
        if (lane >= off) sv += t;
    }
    if (lane == 63) wsum[wid] = sv;
    __syncthreads();
    if (wid == 0) {
        int ws = (lane < 16) ? wsum[lane] : 0;
        #pragma unroll
        for (int off = 1; off < 16; off <<= 1) {
            int t = __shfl_up(ws, off);
            if (lane >= off) ws += t;
        }
        if (lane < 16) wsum[lane] = ws;
    }
    __syncthreads();
    int excl = (wid > 0 ? wsum[wid - 1] : 0) + (sv - v);
    if (i < NN) row_start[i] = excl;
    if (tid == 0) partial[blockIdx.x] = wsum[15];
}

// ---------------- scan stage 2 (merged): add carry, emit cursor copy, write total ----------------
__global__ __launch_bounds__(1024) void k_scan3(int* __restrict__ row_start, const int* __restrict__ partial,
                                                int* __restrict__ cursor, int nb) {
    __shared__ int sh_carry, sh_all;
    int tid = threadIdx.x;
    if (tid < 64) {
        int v = (tid < nb) ? partial[tid] : 0;
        int lt = (tid < (int)blockIdx.x) ? v : 0;
        #pragma unroll
        for (int off = 32; off; off >>= 1) {
            lt += __shfl_down(lt, off);
            v  += __shfl_down(v, off);
        }
        if (tid == 0) { sh_carry = lt; sh_all = v; }
    }
    __syncthreads();
    int i = blockIdx.x * 1024 + tid;
    if (i < NN) {
        int val = row_start[i] + sh_carry;
        row_start[i] = val;
        cursor[i] = val;
    }
    if (blockIdx.x == 0 && tid == 0) row_start[NN] = sh_all;
}

// ---------------- CSR bucket fill (cursor-based) ----------------
__global__ void k_fill_csr(const int* __restrict__ src, const int* __restrict__ dst,
                           int* __restrict__ cursor, int* __restrict__ csr_src, int n) {
    int e = blockIdx.x * blockDim.x + threadIdx.x;
    if (e < n) {
        int d = __builtin_nontemporal_load(dst + e);
        int sv = __builtin_nontemporal_load(src + e);
        int pos = atomicAdd(&cursor[d], 1);
        csr_src[pos] = sv;
    }
}

// ---------------- converts ----------------
__global__ void k_cvt_h(const float* __restrict__ h, unsigned short* __restrict__ hb) {
    int i = blockIdx.x * 256 + threadIdx.x;
    if (i < NN * HID / 4) {
        float4 v = reinterpret_cast<const float4*>(h)[i];
        ushort4 o;
        o.x = f2bf(v.x); o.y = f2bf(v.y); o.z = f2bf(v.z); o.w = f2bf(v.w);
        reinterpret_cast<ushort4*>(hb)[i] = o;
    }
}

// W[384][128] fp32 -> fragment-ordered bf16: frag_id = kseg*32 + cf*4 + kb (kseg-major
// so each kseg chunk is one contiguous 32 KB block for LDS staging).
// Lane's 8 elems: W[(kseg*128 + kb*32 + kg*8 + j)*128 + cf*16 + r], r=lane&15, kg=lane>>4.
__global__ void k_cvt_wfrag(const float* __restrict__ W1, const float* __restrict__ W2,
                            unsigned short* __restrict__ F1, unsigned short* __restrict__ F2) {
    int t = blockIdx.x * 256 + threadIdx.x;
    if (t >= 12288) return;
    int m = t / 6144;
    int u = t - m * 6144;        // 0..6143
    int frag = u >> 6;           // 0..95
    int lane = u & 63;
    int kseg = frag >> 5;
    int cf = (frag >> 2) & 7;
    int kb = frag & 3;
    int r = lane & 15, kg = lane >> 4;
    int c = cf * 16 + r;
    int kbase = kseg * 128 + kb * 32 + kg * 8;
    const float* __restrict__ W = m ? W2 : W1;
    unsigned short* __restrict__ F = m ? F2 : F1;
    unsigned short* __restrict__ o = F + ((size_t)frag * 64 + lane) * 8;
    #pragma unroll
    for (int j = 0; j < 8; ++j)
        o[j] = f2bf(W[(size_t)(kbase + j) * HID + c]);
}

// ---------------- propagation: one node per 64-lane wave (r6 structure, proven) ----------------
__global__ __launch_bounds__(256) void k_prop_bf(const unsigned short* __restrict__ x, const float* __restrict__ norm,
                                                 const int* __restrict__ row_start, const int* __restrict__ csr_src,
                                                 unsigned short* __restrict__ y) {
    int node = blockIdx.x * 4 + threadIdx.y;
    int lane = threadIdx.x;
    int h = lane >> 5;
    int sub = lane & 31;
    int colb = sub * 4;
    float a0 = 0.f, a1 = 0.f, a2 = 0.f, a3 = 0.f;
    int s = row_start[node], e = row_start[node + 1];
    int i = s + h;
    if (i + 6 < e) {
        int c0 = csr_src[i], c1 = csr_src[i + 2], c2 = csr_src[i + 4], c3 = csr_src[i + 6];
        int j = i + 8;
        while (true) {
            bool more = (j + 6 < e);
            int n0, n1, n2, n3;
            if (more) {
                n0 = csr_src[j]; n1 = csr_src[j + 2]; n2 = csr_src[j + 4]; n3 = csr_src[j + 6];
            }
            float s0 = norm[c0], s1 = norm[c1], s2 = norm[c2], s3 = norm[c3];
            ushort4 v0 = *reinterpret_cast<const ushort4*>(x + (size_t)c0 * HID + colb);
            ushort4 v1 = *reinterpret_cast<const ushort4*>(x + (size_t)c1 * HID + colb);
            ushort4 v2 = *reinterpret_cast<const ushort4*>(x + (size_t)c2 * HID + colb);
            ushort4 v3 = *reinterpret_cast<const ushort4*>(x + (size_t)c3 * HID + colb);
            a0 += s0 * bf2f(v0.x) + s1 * bf2f(v1.x) + s2 * bf2f(v2.x) + s3 * bf2f(v3.x);
            a1 += s0 * bf2f(v0.y) + s1 * bf2f(v1.y) + s2 * bf2f(v2.y) + s3 * bf2f(v3.y);
            a2 += s0 * bf2f(v0.z) + s1 * bf2f(v1.z) + s2 * bf2f(v2.z) + s3 * bf2f(v3.z);
            a3 += s0 * bf2f(v0.w) + s1 * bf2f(v1.w) + s2 * bf2f(v2.w) + s3 * bf2f(v3.w);
            i = j;
            if (!more) break;
            c0 = n0; c1 = n1; c2 = n2; c3 = n3;
            j += 8;
        }
    }
    for (; i < e; i += 2) {
        int sn = csr_src[i];
        float ns = norm[sn];
        ushort4 v = *reinterpret_cast<const ushort4*>(x + (size_t)sn * HID + colb);
        a0 += ns * bf2f(v.x); a1 += ns * bf2f(v.y); a2 += ns * bf2f(v.z); a3 += ns * bf2f(v.w);
    }
    a0 += __shfl_xor(a0, 32);
    a1 += __shfl_xor(a1, 32);
    a2 += __shfl_xor(a2, 32);
    a3 += __shfl_xor(a3, 32);
    if (h == 0) {
        float nd = norm[node];
        ushort4 o;
        o.x = f2bf(nd * a0); o.y = f2bf(nd * a1); o.z = f2bf(nd * a2); o.w = f2bf(nd * a3);
        *reinterpret_cast<ushort4*>(y + (size_t)node * HID + colb) = o;
    }
}

// ---------------- MFMA GEMM: LDS-staged B (32 KB per kseg), 2 waves x 16 rows ----------------
// Pool path (y==nullptr): LDS pre-reduction, ~1 atomicMax per (block,col).
__global__ __launch_bounds__(128) void k_gemm_mfma(const unsigned short* __restrict__ x0,
                                                   const unsigned short* __restrict__ x1,
                                                   const unsigned short* __restrict__ x2,
                                                   const unsigned short* __restrict__ Wfrag,
                                                   const float* __restrict__ bias,
                                                   unsigned short* __restrict__ y,
                                                   const int* __restrict__ gid,
                                                   float* __restrict__ pooled) {
    __shared__ __align__(16) char smem[32768];
    __shared__ int sgid[32];
    int tid = threadIdx.x;
    int wave = tid >> 6;
    int lane = tid & 63;
    int r = lane & 15, kg = lane >> 4;
    int brow = blockIdx.x * 32;
    int row0 = brow + wave * 16;
    const unsigned short* xs[3] = { x0, x1, x2 };

    f32x4 acc[8];
    #pragma unroll
    for (int cf = 0; cf < 8; ++cf) acc[cf] = (f32x4){0.f, 0.f, 0.f, 0.f};

    for (int kseg = 0; kseg < 3; ++kseg) {
        // stage this kseg's 32 frags (32 KB, contiguous) into LDS
        const float4* __restrict__ srcv = reinterpret_cast<const float4*>(Wfrag + (size_t)kseg * 16384);
        float4* dstv = reinterpret_cast<float4*>(smem);
        #pragma unroll
        for (int i = 0; i < 16; ++i) dstv[tid + 128 * i] = srcv[tid + 128 * i];
        __syncthreads();
        const unsigned short* __restrict__ xp = xs[kseg] + (size_t)(row0 + r) * HID;
        #pragma unroll
        for (int kb = 0; kb < 4; ++kb) {
            bf16x8 afrag = *reinterpret_cast<const bf16x8*>(xp + kb * 32 + kg * 8);
            #pragma unroll
            for (int cf = 0; cf < 8; ++cf) {
                bf16x8 bfrag = *reinterpret_cast<const bf16x8*>(smem + ((cf * 4 + kb) * 64 + lane) * 16);
                acc[cf] = __builtin_amdgcn_mfma_f32_16x16x32_bf16(afrag, bfrag, acc[cf], 0, 0, 0);
            }
        }
        __syncthreads();
    }

    int colr = lane & 15;
    int vb = (lane >> 4) * 4;
    if (y) {
        int orow = row0 + vb;
        #pragma unroll
        for (int cf = 0; cf < 8; ++cf) {
            int col = cf * 16 + colr;
            float bb = bias[col];
            #pragma unroll
            for (int v = 0; v < 4; ++v) {
                float val = fmaxf(acc[cf][v] + bb, 0.f);
                y[(size_t)(orow + v) * HID + col] = f2bf(val);
            }
        }
    } else {
        // stage block outputs in LDS: sval[32 rows][129 pitch]
        float* sval = reinterpret_cast<float*>(smem);
        #pragma unroll
        for (int cf = 0; cf < 8; ++cf) {
            int col = cf * 16 + colr;
            float bb = bias[col];
            #pragma unroll
            for (int v = 0; v < 4; ++v)
                sval[(wave * 16 + vb + v) * 129 + col] = fmaxf(acc[cf][v] + bb, 0.f);
        }
        if (tid < 32) sgid[tid] = gid[brow + tid];
        __syncthreads();
        // thread tid owns column tid; walk 32 rows with flush-on-gid-change
        float m = 0.f;
        int cg = sgid[0];
        #pragma unroll 4
        for (int rr = 0; rr < 32; ++rr) {
            int g = sgid[rr];
            float val = sval[rr * 129 + tid];
            if (g != cg) {
                atomicMax((unsigned int*)&pooled[cg * HID + tid], __float_as_uint(m));
                m = 0.f; cg = g;
            }
            m = fmaxf(m, val);
        }
        atomicMax((unsigned int*)&pooled[cg * HID + tid], __float_as_uint(m));
    }
}

// ---------------- final head ----------------
__global__ void k_head(const float* __restrict__ pooled, const float* __restrict__ Wc,
                       const float* __restrict__ bc, float* __restrict__ out) {
    int t = threadIdx.x;
    if (t < NGRAPH * NCLS) {
        int g = t / NCLS, c = t % NCLS;
        float acc = bc[c];
        for (int k = 0; k < HID; ++k) acc += pooled[g * HID + k] * Wc[k * NCLS + c];
        out[t] = acc;
    }
}

extern "C" void kernel_launch(void* const* d_in, const int* in_sizes, int n_in,
                              void* d_out, int out_size, void* d_ws, size_t ws_size,
                              hipStream_t stream) {
    const float* h   = (const float*)d_in[0];
    const int*   src = (const int*)d_in[1];
    const int*   dst = (const int*)d_in[2];
    const int*   gid = (const int*)d_in[3];
    const float* W1  = (const float*)d_in[4];
    const float* b1  = (const float*)d_in[5];
    const float* W2  = (const float*)d_in[6];
    const float* b2  = (const float*)d_in[7];
    const float* Wc  = (const float*)d_in[8];
    const float* bc  = (const float*)d_in[9];
    float* out = (float*)d_out;

    char* ws = (char*)d_ws;
    size_t off = 0;
    auto alloc = [&](size_t bytes) { void* p = ws + off; off = (off + bytes + 63) & ~(size_t)63; return p; };
    int*   deg       = (int*)alloc((size_t)NN * 4);
    int*   cursor    = (int*)alloc((size_t)NN * 4);
    int*   row_start = (int*)alloc((size_t)(NN + 1) * 4);
    int*   csr_src   = (int*)alloc((size_t)NE * 4);
    float* norm      = (float*)alloc((size_t)NN * 4);
    int*   partial   = (int*)alloc(64 * 4);
    float* pooled    = (float*)alloc((size_t)NGRAPH * HID * 4);
    unsigned short* Wf1 = (unsigned short*)alloc((size_t)384 * HID * 2);
    unsigned short* Wf2 = (unsigned short*)alloc((size_t)384 * HID * 2);
    const size_t FB = (size_t)NN * HID * 2;
    unsigned short* hb  = (unsigned short*)alloc(FB);
    unsigned short* Bb  = (unsigned short*)alloc(FB);
    unsigned short* Cb  = (unsigned short*)alloc(FB);
    unsigned short* Yb  = (unsigned short*)alloc(FB);

    hipMemsetAsync(deg, 0, (size_t)NN * 4, stream);
    hipMemsetAsync(pooled, 0, (size_t)NGRAPH * HID * 4, stream);

    const int EB = 256;
    const int SCAN_BLOCKS = (NN + 1023) / 1024;  // 40

    // converts first (independent of graph build)
    k_cvt_h<<<(NN * HID / 4 + 255) / 256, 256, 0, stream>>>(h, hb);
    k_cvt_wfrag<<<48, 256, 0, stream>>>(W1, W2, Wf1, Wf2);

    // CSR build
    k_count_deg<<<(NE + EB - 1) / EB, EB, 0, stream>>>(dst, deg, NE);
    k_scan1<<<SCAN_BLOCKS, 1024, 0, stream>>>(deg, row_start, partial, norm);
    k_scan3<<<SCAN_BLOCKS, 1024, 0, stream>>>(row_start, partial, cursor, SCAN_BLOCKS);
    k_fill_csr<<<(NE + EB - 1) / EB, EB, 0, stream>>>(src, dst, cursor, csr_src, NE);

    dim3 pblk(64, 4);
    int pblocks = NN / 4;     // 10000
    int gblocks = NN / 32;    // 1250

    // layer 1
    k_prop_bf<<<pblocks, pblk, 0, stream>>>(hb, norm, row_start, csr_src, Bb);
    k_prop_bf<<<pblocks, pblk, 0, stream>>>(Bb, norm, row_start, csr_src, Cb);
    k_gemm_mfma<<<gblocks, 128, 0, stream>>>(hb, Bb, Cb, Wf1, b1, Yb, nullptr, nullptr);

    // layer 2 (fused LDS-reduced max-pool epilogue; no Z buffer)
    k_prop_bf<<<pblocks, pblk, 0, stream>>>(Yb, norm, row_start, csr_src, Bb);
    k_prop_bf<<<pblocks, pblk, 0, stream>>>(Bb, norm, row_start, csr_src, Cb);
    k_gemm_mfma<<<gblocks, 128, 0, stream>>>(Yb, Bb, Cb, Wf2, b2, nullptr, gid, pooled);

    // head
    k_head<<<1, 192, 0, stream>>>(pooled, Wc, bc, out);
}

// Round 12
// 223.691 us; speedup vs baseline: 1.4687x; 1.0754x over previous
//
#include <hip/hip_runtime.h>
#include <hip/hip_bf16.h>

#define NN 40000
#define NE 640000
#define HID 128
#define NCLS 10
#define NGRAPH 16

typedef __attribute__((ext_vector_type(8))) short bf16x8;
typedef __attribute__((ext_vector_type(4))) float f32x4;

__device__ inline float bf2f(unsigned short u) {
    unsigned int x = ((unsigned int)u) << 16;
    return __builtin_bit_cast(float, x);
}
__device__ inline unsigned short f2bf(float f) {
    __hip_bfloat16 h = __float2bfloat16(f);
    return __builtin_bit_cast(unsigned short, h);
}

// ---------------- A: deg zero (40 blocks) + W frag convert (48 blocks) ----------------
// W[384][128] fp32 -> fragment-ordered bf16: frag_id = kseg*32 + cf*4 + kb (kseg-major).
__global__ void k_prep(const float* __restrict__ W1, const float* __restrict__ W2,
                       unsigned short* __restrict__ F1, unsigned short* __restrict__ F2,
                       int* __restrict__ deg) {
    if (blockIdx.x < 40) {
        int i = blockIdx.x * 256 + threadIdx.x;
        if (i < 10000) reinterpret_cast<int4*>(deg)[i] = make_int4(0, 0, 0, 0);
        return;
    }
    int t = (blockIdx.x - 40) * 256 + threadIdx.x;
    if (t >= 12288) return;
    int m = t / 6144;
    int u = t - m * 6144;
    int frag = u >> 6;
    int lane = u & 63;
    int kseg = frag >> 5;
    int cf = (frag >> 2) & 7;
    int kb = frag & 3;
    int r = lane & 15, kg = lane >> 4;
    int c = cf * 16 + r;
    int kbase = kseg * 128 + kb * 32 + kg * 8;
    const float* __restrict__ W = m ? W2 : W1;
    unsigned short* __restrict__ F = m ? F2 : F1;
    unsigned short* __restrict__ o = F + ((size_t)frag * 64 + lane) * 8;
    #pragma unroll
    for (int j = 0; j < 8; ++j)
        o[j] = f2bf(W[(size_t)(kbase + j) * HID + c]);
}

// ---------------- B: count_deg (2500 blocks) + cvt_h (5000 blocks) ----------------
__global__ void k_count_cvt(const int* __restrict__ dst, int* __restrict__ deg,
                            const float* __restrict__ h, unsigned short* __restrict__ hb) {
    if (blockIdx.x < 2500) {
        int e = blockIdx.x * 256 + threadIdx.x;
        if (e < NE) atomicAdd(&deg[__builtin_nontemporal_load(dst + e)], 1);
        return;
    }
    int i = (blockIdx.x - 2500) * 256 + threadIdx.x;
    if (i < NN * HID / 4) {
        float4 v = reinterpret_cast<const float4*>(h)[i];
        ushort4 o;
        o.x = f2bf(v.x); o.y = f2bf(v.y); o.z = f2bf(v.z); o.w = f2bf(v.w);
        reinterpret_cast<ushort4*>(hb)[i] = o;
    }
}

// ---------------- scan stage 1: per-block exclusive scan + block totals (+ fused norm) ----------------
__global__ __launch_bounds__(1024) void k_scan1(const int* __restrict__ deg, int* __restrict__ row_start,
                                                int* __restrict__ partial, float* __restrict__ norm) {
    __shared__ int wsum[16];
    int tid = threadIdx.x, lane = tid & 63, wid = tid >> 6;
    int i = blockIdx.x * 1024 + tid;
    int v = (i < NN) ? deg[i] : 0;
    if (i < NN) norm[i] = rsqrtf(fmaxf((float)v, 1.0f));
    int sv = v;
    #pragma unroll
    for (int off = 1; off < 64; off <<= 1) {
        int t = __shfl_up(sv, off);
        if (lane >= off) sv += t;
    }
    if (lane == 63) wsum[wid] = sv;
    __syncthreads();
    if (wid == 0) {
        int ws = (lane < 16) ? wsum[lane] : 0;
        #pragma unroll
        for (int off = 1; off < 16; off <<= 1) {
            int t = __shfl_up(ws, off);
            if (lane >= off) ws += t;
        }
        if (lane < 16) wsum[lane] = ws;
    }
    __syncthreads();
    int excl = (wid > 0 ? wsum[wid - 1] : 0) + (sv - v);
    if (i < NN) row_start[i] = excl;
    if (tid == 0) partial[blockIdx.x] = wsum[15];
}

// ---------------- scan stage 2: add carry, emit cursor, write total (+ zero pooled in block 0) ----------------
__global__ __launch_bounds__(1024) void k_scan3(int* __restrict__ row_start, const int* __restrict__ partial,
                                                int* __restrict__ cursor, int nb, float* __restrict__ pooled) {
    __shared__ int sh_carry, sh_all;
    int tid = threadIdx.x;
    if (tid < 64) {
        int v = (tid < nb) ? partial[tid] : 0;
        int lt = (tid < (int)blockIdx.x) ? v : 0;
        #pragma unroll
        for (int off = 32; off; off >>= 1) {
            lt += __shfl_down(lt, off);
            v  += __shfl_down(v, off);
        }
        if (tid == 0) { sh_carry = lt; sh_all = v; }
    }
    __syncthreads();
    int i = blockIdx.x * 1024 + tid;
    if (i < NN) {
        int val = row_start[i] + sh_carry;
        row_start[i] = val;
        cursor[i] = val;
    }
    if (blockIdx.x == 0) {
        pooled[tid] = 0.f;
        pooled[tid + 1024] = 0.f;
        if (tid == 0) row_start[NN] = sh_all;
    }
}

// ---------------- CSR bucket fill (cursor-based) ----------------
__global__ void k_fill_csr(const int* __restrict__ src, const int* __restrict__ dst,
                           int* __restrict__ cursor, int* __restrict__ csr_src, int n) {
    int e = blockIdx.x * blockDim.x + threadIdx.x;
    if (e < n) {
        int d = __builtin_nontemporal_load(dst + e);
        int sv = __builtin_nontemporal_load(src + e);
        int pos = atomicAdd(&cursor[d], 1);
        csr_src[pos] = sv;
    }
}

// ---------------- propagation: one node per 64-lane wave (r6 structure, proven) ----------------
__global__ __launch_bounds__(256) void k_prop_bf(const unsigned short* __restrict__ x, const float* __restrict__ norm,
                                                 const int* __restrict__ row_start, const int* __restrict__ csr_src,
                                                 unsigned short* __restrict__ y) {
    int node = blockIdx.x * 4 + threadIdx.y;
    int lane = threadIdx.x;
    int h = lane >> 5;
    int sub = lane & 31;
    int colb = sub * 4;
    float a0 = 0.f, a1 = 0.f, a2 = 0.f, a3 = 0.f;
    int s = row_start[node], e = row_start[node + 1];
    int i = s + h;
    if (i + 6 < e) {
        int c0 = csr_src[i], c1 = csr_src[i + 2], c2 = csr_src[i + 4], c3 = csr_src[i + 6];
        int j = i + 8;
        while (true) {
            bool more = (j + 6 < e);
            int n0, n1, n2, n3;
            if (more) {
                n0 = csr_src[j]; n1 = csr_src[j + 2]; n2 = csr_src[j + 4]; n3 = csr_src[j + 6];
            }
            float s0 = norm[c0], s1 = norm[c1], s2 = norm[c2], s3 = norm[c3];
            ushort4 v0 = *reinterpret_cast<const ushort4*>(x + (size_t)c0 * HID + colb);
            ushort4 v1 = *reinterpret_cast<const ushort4*>(x + (size_t)c1 * HID + colb);
            ushort4 v2 = *reinterpret_cast<const ushort4*>(x + (size_t)c2 * HID + colb);
            ushort4 v3 = *reinterpret_cast<const ushort4*>(x + (size_t)c3 * HID + colb);
            a0 += s0 * bf2f(v0.x) + s1 * bf2f(v1.x) + s2 * bf2f(v2.x) + s3 * bf2f(v3.x);
            a1 += s0 * bf2f(v0.y) + s1 * bf2f(v1.y) + s2 * bf2f(v2.y) + s3 * bf2f(v3.y);
            a2 += s0 * bf2f(v0.z) + s1 * bf2f(v1.z) + s2 * bf2f(v2.z) + s3 * bf2f(v3.z);
            a3 += s0 * bf2f(v0.w) + s1 * bf2f(v1.w) + s2 * bf2f(v2.w) + s3 * bf2f(v3.w);
            i = j;
            if (!more) break;
            c0 = n0; c1 = n1; c2 = n2; c3 = n3;
            j += 8;
        }
    }
    for (; i < e; i += 2) {
        int sn = csr_src[i];
        float ns = norm[sn];
        ushort4 v = *reinterpret_cast<const ushort4*>(x + (size_t)sn * HID + colb);
        a0 += ns * bf2f(v.x); a1 += ns * bf2f(v.y); a2 += ns * bf2f(v.z); a3 += ns * bf2f(v.w);
    }
    a0 += __shfl_xor(a0, 32);
    a1 += __shfl_xor(a1, 32);
    a2 += __shfl_xor(a2, 32);
    a3 += __shfl_xor(a3, 32);
    if (h == 0) {
        float nd = norm[node];
        ushort4 o;
        o.x = f2bf(nd * a0); o.y = f2bf(nd * a1); o.z = f2bf(nd * a2); o.w = f2bf(nd * a3);
        *reinterpret_cast<ushort4*>(y + (size_t)node * HID + colb) = o;
    }
}

// ---------------- MFMA GEMM: 256 thr / 64 rows / 4 waves, LDS-staged B, optional fused pool ----------------
__global__ __launch_bounds__(256) void k_gemm_mfma(const unsigned short* __restrict__ x0,
                                                   const unsigned short* __restrict__ x1,
                                                   const unsigned short* __restrict__ x2,
                                                   const unsigned short* __restrict__ Wfrag,
                                                   const float* __restrict__ bias,
                                                   unsigned short* __restrict__ y,
                                                   const int* __restrict__ gid,
                                                   float* __restrict__ pooled) {
    __shared__ __align__(16) char smem[33024];   // max(32768 staging, 64*129*4 pool vals)
    __shared__ int sgid[64];
    int tid = threadIdx.x;
    int wave = tid >> 6;
    int lane = tid & 63;
    int r = lane & 15, kg = lane >> 4;
    int brow = blockIdx.x * 64;
    int row0 = brow + wave * 16;
    const unsigned short* xs[3] = { x0, x1, x2 };

    f32x4 acc[8];
    #pragma unroll
    for (int cf = 0; cf < 8; ++cf) acc[cf] = (f32x4){0.f, 0.f, 0.f, 0.f};

    for (int kseg = 0; kseg < 3; ++kseg) {
        // stage this kseg's 32 frags (32 KB contiguous) into LDS
        const float4* __restrict__ srcv = reinterpret_cast<const float4*>(Wfrag + (size_t)kseg * 16384);
        float4* dstv = reinterpret_cast<float4*>(smem);
        #pragma unroll
        for (int i = 0; i < 8; ++i) dstv[tid + 256 * i] = srcv[tid + 256 * i];
        __syncthreads();
        const unsigned short* __restrict__ xp = xs[kseg] + (size_t)(row0 + r) * HID;
        #pragma unroll
        for (int kb = 0; kb < 4; ++kb) {
            bf16x8 afrag = *reinterpret_cast<const bf16x8*>(xp + kb * 32 + kg * 8);
            #pragma unroll
            for (int cf = 0; cf < 8; ++cf) {
                bf16x8 bfrag = *reinterpret_cast<const bf16x8*>(smem + ((cf * 4 + kb) * 64 + lane) * 16);
                acc[cf] = __builtin_amdgcn_mfma_f32_16x16x32_bf16(afrag, bfrag, acc[cf], 0, 0, 0);
            }
        }
        __syncthreads();
    }

    int colr = lane & 15;
    int vb = (lane >> 4) * 4;
    if (y) {
        int orow = row0 + vb;
        #pragma unroll
        for (int cf = 0; cf < 8; ++cf) {
            int col = cf * 16 + colr;
            float bb = bias[col];
            #pragma unroll
            for (int v = 0; v < 4; ++v) {
                float val = fmaxf(acc[cf][v] + bb, 0.f);
                y[(size_t)(orow + v) * HID + col] = f2bf(val);
            }
        }
    } else {
        // stage block outputs in LDS: sval[64 rows][129 pitch]
        float* sval = reinterpret_cast<float*>(smem);
        #pragma unroll
        for (int cf = 0; cf < 8; ++cf) {
            int col = cf * 16 + colr;
            float bb = bias[col];
            #pragma unroll
            for (int v = 0; v < 4; ++v)
                sval[(wave * 16 + vb + v) * 129 + col] = fmaxf(acc[cf][v] + bb, 0.f);
        }
        if (tid < 64) sgid[tid] = gid[brow + tid];
        __syncthreads();
        // 256 threads: col = tid&127, half = tid>>7 walks 32 rows
        int col = tid & 127;
        int rbase = (tid >> 7) * 32;
        float m = 0.f;
        int cg = sgid[rbase];
        #pragma unroll 4
        for (int rr = rbase; rr < rbase + 32; ++rr) {
            int g = sgid[rr];
            float val = sval[rr * 129 + col];
            if (g != cg) {
                atomicMax((unsigned int*)&pooled[cg * HID + col], __float_as_uint(m));
                m = 0.f; cg = g;
            }
            m = fmaxf(m, val);
        }
        atomicMax((unsigned int*)&pooled[cg * HID + col], __float_as_uint(m));
    }
}

// ---------------- final head ----------------
__global__ void k_head(const float* __restrict__ pooled, const float* __restrict__ Wc,
                       const float* __restrict__ bc, float* __restrict__ out) {
    int t = threadIdx.x;
    if (t < NGRAPH * NCLS) {
        int g = t / NCLS, c = t % NCLS;
        float acc = bc[c];
        for (int k = 0; k < HID; ++k) acc += pooled[g * HID + k] * Wc[k * NCLS + c];
        out[t] = acc;
    }
}

extern "C" void kernel_launch(void* const* d_in, const int* in_sizes, int n_in,
                              void* d_out, int out_size, void* d_ws, size_t ws_size,
                              hipStream_t stream) {
    const float* h   = (const float*)d_in[0];
    const int*   src = (const int*)d_in[1];
    const int*   dst = (const int*)d_in[2];
    const int*   gid = (const int*)d_in[3];
    const float* W1  = (const float*)d_in[4];
    const float* b1  = (const float*)d_in[5];
    const float* W2  = (const float*)d_in[6];
    const float* b2  = (const float*)d_in[7];
    const float* Wc  = (const float*)d_in[8];
    const float* bc  = (const float*)d_in[9];
    float* out = (float*)d_out;

    char* ws = (char*)d_ws;
    size_t off = 0;
    auto alloc = [&](size_t bytes) { void* p = ws + off; off = (off + bytes + 63) & ~(size_t)63; return p; };
    int*   deg       = (int*)alloc((size_t)NN * 4);
    int*   cursor    = (int*)alloc((size_t)NN * 4);
    int*   row_start = (int*)alloc((size_t)(NN + 1) * 4);
    int*   csr_src   = (int*)alloc((size_t)NE * 4);
    float* norm      = (float*)alloc((size_t)NN * 4);
    int*   partial   = (int*)alloc(64 * 4);
    float* pooled    = (float*)alloc((size_t)NGRAPH * HID * 4);
    unsigned short* Wf1 = (unsigned short*)alloc((size_t)384 * HID * 2);
    unsigned short* Wf2 = (unsigned short*)alloc((size_t)384 * HID * 2);
    const size_t FB = (size_t)NN * HID * 2;
    unsigned short* hb  = (unsigned short*)alloc(FB);
    unsigned short* Bb  = (unsigned short*)alloc(FB);
    unsigned short* Cb  = (unsigned short*)alloc(FB);
    unsigned short* Yb  = (unsigned short*)alloc(FB);

    const int EB = 256;
    const int SCAN_BLOCKS = (NN + 1023) / 1024;  // 40

    // A: deg zero + W frag convert
    k_prep<<<88, 256, 0, stream>>>(W1, W2, Wf1, Wf2, deg);
    // B: count_deg + cvt_h
    k_count_cvt<<<7500, 256, 0, stream>>>(dst, deg, h, hb);
    // scan (+norm; +pooled zero)
    k_scan1<<<SCAN_BLOCKS, 1024, 0, stream>>>(deg, row_start, partial, norm);
    k_scan3<<<SCAN_BLOCKS, 1024, 0, stream>>>(row_start, partial, cursor, SCAN_BLOCKS, pooled);
    k_fill_csr<<<(NE + EB - 1) / EB, EB, 0, stream>>>(src, dst, cursor, csr_src, NE);

    dim3 pblk(64, 4);
    int pblocks = NN / 4;     // 10000
    int gblocks = NN / 64;    // 625

    // layer 1
    k_prop_bf<<<pblocks, pblk, 0, stream>>>(hb, norm, row_start, csr_src, Bb);
    k_prop_bf<<<pblocks, pblk, 0, stream>>>(Bb, norm, row_start, csr_src, Cb);
    k_gemm_mfma<<<gblocks, 256, 0, stream>>>(hb, Bb, Cb, Wf1, b1, Yb, nullptr, nullptr);

    // layer 2 (fused LDS-reduced max-pool epilogue)
    k_prop_bf<<<pblocks, pblk, 0, stream>>>(Yb, norm, row_start, csr_src, Bb);
    k_prop_bf<<<pblocks, pblk, 0, stream>>>(Bb, norm, row_start, csr_src, Cb);
    k_gemm_mfma<<<gblocks, 256, 0, stream>>>(Yb, Bb, Cb, Wf2, b2, nullptr, gid, pooled);

    // head
    k_head<<<1, 192, 0, stream>>>(pooled, Wc, bc, out);
}